// Round 5
// baseline (95.687 us; speedup 1.0000x reference)
//
#include <hip/hip_runtime.h>
#include <hip/hip_cooperative_groups.h>
#include <math.h>

namespace cg = cooperative_groups;

#define NPTS    18
#define NDIMS   4
#define NITER   15   // num_splines - 1
#define RSTRIDE 28   // floats per table row: 24 used + 4 pad
#define CBLK    1024 // cooperative grid: 4 blocks/CU * 256 CUs
#define NBLK    2048 // fallback grid

__device__ __forceinline__ float sigm(float v) { return 1.0f / (1.0f + expf(-v)); }
__device__ __forceinline__ float dot4(float4 a, float4 b) {
    return fmaf(a.x, b.x, fmaf(a.y, b.y, fmaf(a.z, b.z, a.w * b.w)));
}

// ---------- shared device code: MLP for one point (256 threads) ----------
// Writes P[point*4 + 0..3] (cumsum over dims). Uses h/part LDS scratch.
__device__ __forceinline__ void mlp_point(
    int t, float pos,
    const float* __restrict__ W1, const float* __restrict__ b1,
    const float* __restrict__ W2, const float* __restrict__ b2,
    const float* __restrict__ W3, const float* __restrict__ b3,
    const float* __restrict__ W4, const float* __restrict__ b4,
    const float* __restrict__ W5, const float* __restrict__ b5,
    const float* __restrict__ W6, const float* __restrict__ b6,
    float* __restrict__ Pout,   // global, 4 floats
    float* h1, float* h2, float* h3, float* h4, float* h5, float* z6,
    float* part)
{
    // L1: (1 -> 16) sigmoid
    if (t < 16) h1[t] = sigm(fmaf(W1[t], pos, b1[t]));
    __syncthreads();

    // L2: (16 -> 64) sigmoid
    if (t < 64) {
        const float4* w = (const float4*)(W2 + t * 16);
        const float4* h = (const float4*)h1;
        float a = b2[t] + ((dot4(w[0], h[0]) + dot4(w[1], h[1])) +
                           (dot4(w[2], h[2]) + dot4(w[3], h[3])));
        h2[t] = sigm(a);
    }
    __syncthreads();

    // L3: (64 -> 256) relu
    {
        const float4* w = (const float4*)(W3 + t * 64);
        const float4* h = (const float4*)h2;
        float a0 = 0.f, a1 = 0.f, a2 = 0.f, a3 = 0.f;
        #pragma unroll
        for (int k = 0; k < 16; k += 4) {
            a0 += dot4(w[k + 0], h[k + 0]);
            a1 += dot4(w[k + 1], h[k + 1]);
            a2 += dot4(w[k + 2], h[k + 2]);
            a3 += dot4(w[k + 3], h[k + 3]);
        }
        h3[t] = fmaxf(b3[t] + ((a0 + a1) + (a2 + a3)), 0.f);
    }
    __syncthreads();

    // L4: (256 -> 64) relu, 4 partial-threads per output
    {
        const int o = t & 63, q = t >> 6;
        const float4* w = (const float4*)(W4 + o * 256 + q * 64);
        const float4* h = (const float4*)(h3 + q * 64);
        float a0 = 0.f, a1 = 0.f, a2 = 0.f, a3 = 0.f;
        #pragma unroll
        for (int k = 0; k < 16; k += 4) {
            a0 += dot4(w[k + 0], h[k + 0]);
            a1 += dot4(w[k + 1], h[k + 1]);
            a2 += dot4(w[k + 2], h[k + 2]);
            a3 += dot4(w[k + 3], h[k + 3]);
        }
        part[t] = (a0 + a1) + (a2 + a3);
    }
    __syncthreads();
    if (t < 64)
        h4[t] = fmaxf(b4[t] + ((part[t] + part[t + 64]) + (part[t + 128] + part[t + 192])), 0.f);
    __syncthreads();

    // L5: (64 -> 16) relu, 4 partial-threads per output
    if (t < 64) {
        const int o = t & 15, q = t >> 4;
        const float4* w = (const float4*)(W5 + o * 64 + q * 16);
        const float4* h = (const float4*)(h4 + q * 16);
        part[t] = (dot4(w[0], h[0]) + dot4(w[1], h[1])) +
                  (dot4(w[2], h[2]) + dot4(w[3], h[3]));
    }
    __syncthreads();
    if (t < 16)
        h5[t] = fmaxf(b5[t] + ((part[t] + part[t + 16]) + (part[t + 32] + part[t + 48])), 0.f);
    __syncthreads();

    // L6: (16 -> 4)
    if (t < 4) {
        const float4* w = (const float4*)(W6 + t * 16);
        const float4* h = (const float4*)h5;
        z6[t] = b6[t] + ((dot4(w[0], h[0]) + dot4(w[1], h[1])) +
                         (dot4(w[2], h[2]) + dot4(w[3], h[3])));
    }
    __syncthreads();

    // cumsum over dims
    if (t < 4) {
        float c = 0.f;
        #pragma unroll
        for (int j = 0; j <= 3; ++j) {
            float v = z6[j];
            if (j <= t) c += v;
        }
        Pout[t] = c;
    }
}

// ---------- shared device code: build table in LDS from P, then eval ----------
__device__ __forceinline__ void build_table_lds(int t, const float* __restrict__ P,
                                                float* Praw, float* s)
{
    if (t < NPTS * NDIMS) Praw[t] = P[t];
    __syncthreads();
    if (t < NDIMS) {
        const int j = t;
        float P0 = Praw[0 * NDIMS + j];
        float P1 = Praw[1 * NDIMS + j];
        float P2 = Praw[2 * NDIMS + j];
        #pragma unroll
        for (int i = 0; i < NITER; ++i) {
            float Pnext = Praw[(3 + i) * NDIMS + j];
            float p0 = (P0 + P2) * 0.25f + P1 * 0.5f;
            float p2 = Pnext;
            float p1 = 2.0f * (P2 - (p0 + p2) * 0.25f);
            float* row = s + i * RSTRIDE;
            row[0 * 4 + j] = P0; row[1 * 4 + j] = P1; row[2 * 4 + j] = P2;
            row[3 * 4 + j] = p0; row[4 * 4 + j] = p1; row[5 * 4 + j] = p2;
            P0 = p0; P1 = p1; P2 = p2;
        }
    }
    __syncthreads();
}

__device__ __forceinline__ float4 eval_one(float xc, const float* s)
{
    float u  = xc * 15.0f;
    float fi = floorf(u);
    fi = fminf(fmaxf(fi, 0.0f), 14.0f);   // last matching choice == floor bucket
    float d  = (u - fi) * 0.5f;           // in [0, 0.5]

    const float* row = s + (int)fi * RSTRIDE;
    float4 Pt0 = *(const float4*)(row + 0);
    float4 Pt1 = *(const float4*)(row + 4);
    float4 Pt2 = *(const float4*)(row + 8);
    float4 Pn0 = *(const float4*)(row + 12);
    float4 Pn1 = *(const float4*)(row + 16);
    float4 Pn2 = *(const float4*)(row + 20);

    float dp  = d + 0.5f, omp = 0.5f - d;
    float cp0 = omp * omp, cp1 = 2.0f * dp * omp, cp2 = dp * dp;
    float omd = 1.0f - d;
    float cc0 = omd * omd, cc1 = 2.0f * d * omd, cc2 = d * d;

    // wc = cos^2(pi d); ws = 1 - wc (exact identity)
    float wc = fmaf(0.5f, cospif(2.0f * d), 0.5f);

    float4 r;
    {
        float fp = fmaf(cp0, Pt0.x, fmaf(cp1, Pt1.x, cp2 * Pt2.x));
        float fc = fmaf(cc0, Pn0.x, fmaf(cc1, Pn1.x, cc2 * Pn2.x));
        r.x = fmaf(wc, fp - fc, fc);
    }
    {
        float fp = fmaf(cp0, Pt0.y, fmaf(cp1, Pt1.y, cp2 * Pt2.y));
        float fc = fmaf(cc0, Pn0.y, fmaf(cc1, Pn1.y, cc2 * Pn2.y));
        r.y = fmaf(wc, fp - fc, fc);
    }
    {
        float fp = fmaf(cp0, Pt0.z, fmaf(cp1, Pt1.z, cp2 * Pt2.z));
        float fc = fmaf(cc0, Pn0.z, fmaf(cc1, Pn1.z, cc2 * Pn2.z));
        r.z = fmaf(wc, fp - fc, fc);
    }
    {
        float fp = fmaf(cp0, Pt0.w, fmaf(cp1, Pt1.w, cp2 * Pt2.w));
        float fc = fmaf(cc0, Pn0.w, fmaf(cc1, Pn1.w, cc2 * Pn2.w));
        r.w = fmaf(wc, fp - fc, fc);
    }
    return r;
}

// ---------------- Fused cooperative kernel ----------------
__global__ __launch_bounds__(256, 4) void fused_kernel(
    const float* __restrict__ x,
    const float* __restrict__ W1, const float* __restrict__ b1,
    const float* __restrict__ W2, const float* __restrict__ b2,
    const float* __restrict__ W3, const float* __restrict__ b3,
    const float* __restrict__ W4, const float* __restrict__ b4,
    const float* __restrict__ W5, const float* __restrict__ b5,
    const float* __restrict__ W6, const float* __restrict__ b6,
    float* __restrict__ P, float4* __restrict__ out4, int n)
{
    __shared__ float h3[256];
    __shared__ float part[256];
    __shared__ float h2[64], h4[64], h1[16], h5[16], z6[4];
    __shared__ float Praw[NPTS * NDIMS];
    __shared__ float s[NITER * RSTRIDE];

    const int t = threadIdx.x;
    const int bid = blockIdx.x;

    // Phase 1: blocks 0..17 compute the MLP for their point.
    if (bid < NPTS) {
        mlp_point(t, (float)(bid + 1), W1, b1, W2, b2, W3, b3, W4, b4, W5, b5, W6, b6,
                  P + bid * NDIMS, h1, h2, h3, h4, h5, z6, part);
        __threadfence();   // make P visible device-wide before the grid barrier
    }

    cg::this_grid().sync();

    // Phase 2: every block builds the table in LDS and streams elements.
    build_table_lds(t, P, Praw, s);

    const int stride = CBLK * 256;
    for (int i = bid * 256 + t; i < n; i += stride)
        out4[i] = eval_one(x[i], s);
}

// ---------------- Fallback kernels (2-launch path) ----------------
__global__ __launch_bounds__(256) void mlp_kernel(
    const float* __restrict__ W1, const float* __restrict__ b1,
    const float* __restrict__ W2, const float* __restrict__ b2,
    const float* __restrict__ W3, const float* __restrict__ b3,
    const float* __restrict__ W4, const float* __restrict__ b4,
    const float* __restrict__ W5, const float* __restrict__ b5,
    const float* __restrict__ W6, const float* __restrict__ b6,
    float* __restrict__ P)
{
    __shared__ float h3[256];
    __shared__ float part[256];
    __shared__ float h2[64], h4[64], h1[16], h5[16], z6[4];
    mlp_point(threadIdx.x, (float)(blockIdx.x + 1), W1, b1, W2, b2, W3, b3,
              W4, b4, W5, b5, W6, b6, P + blockIdx.x * NDIMS,
              h1, h2, h3, h4, h5, z6, part);
}

__global__ __launch_bounds__(256) void spline_kernel(
    const float* __restrict__ x, const float* __restrict__ P,
    float4* __restrict__ out4, int n)
{
    __shared__ float Praw[NPTS * NDIMS];
    __shared__ float s[NITER * RSTRIDE];
    const int t = threadIdx.x;
    build_table_lds(t, P, Praw, s);

    const int stride = NBLK * 256;
    for (int i = blockIdx.x * 256 + t; i < n; i += stride)
        out4[i] = eval_one(x[i], s);
}

// ---------------- launch ----------------
extern "C" void kernel_launch(void* const* d_in, const int* in_sizes, int n_in,
                              void* d_out, int out_size, void* d_ws, size_t ws_size,
                              hipStream_t stream)
{
    const float* x  = (const float*)d_in[0];
    const float* W1 = (const float*)d_in[1];  const float* b1 = (const float*)d_in[2];
    const float* W2 = (const float*)d_in[3];  const float* b2 = (const float*)d_in[4];
    const float* W3 = (const float*)d_in[5];  const float* b3 = (const float*)d_in[6];
    const float* W4 = (const float*)d_in[7];  const float* b4 = (const float*)d_in[8];
    const float* W5 = (const float*)d_in[9];  const float* b5 = (const float*)d_in[10];
    const float* W6 = (const float*)d_in[11]; const float* b6 = (const float*)d_in[12];

    float* P = (float*)d_ws;   // 72 floats
    int n = in_sizes[0];
    float4* out4 = (float4*)d_out;

    void* args[] = {
        (void*)&x,
        (void*)&W1, (void*)&b1, (void*)&W2, (void*)&b2, (void*)&W3, (void*)&b3,
        (void*)&W4, (void*)&b4, (void*)&W5, (void*)&b5, (void*)&W6, (void*)&b6,
        (void*)&P, (void*)&out4, (void*)&n
    };

    hipError_t err = hipLaunchCooperativeKernel(
        (void*)fused_kernel, dim3(CBLK), dim3(256), args, 0, stream);

    if (err != hipSuccess) {
        // Fallback: proven 2-kernel path.
        mlp_kernel<<<NPTS, 256, 0, stream>>>(W1, b1, W2, b2, W3, b3, W4, b4,
                                             W5, b5, W6, b6, P);
        const int blocks = min(NBLK, (n + 255) / 256);
        spline_kernel<<<blocks, 256, 0, stream>>>(x, P, out4, n);
    }
}

// Round 6
// 39.130 us; speedup vs baseline: 2.4453x; 2.4453x over previous
//
#include <hip/hip_runtime.h>
#include <math.h>

#define NPTS    18
#define NDIMS   4
#define NITER   15   // num_splines - 1
#define RSTRIDE 28   // floats per table row: 20 used + 8 pad (112 B stride; measured 0 bank conflicts)
#define NBLK    2048
#define CHUNK   1024 // elements per block per sweep (4 per thread, wave-strided)

__device__ __forceinline__ float sigm(float v) { return 1.0f / (1.0f + expf(-v)); }
__device__ __forceinline__ float dot4(float4 a, float4 b) {
    return fmaf(a.x, b.x, fmaf(a.y, b.y, fmaf(a.z, b.z, a.w * b.w)));
}

// ---------------- Kernel A: tiny MLP, one block per control point, 512 threads ----------------
// All weight loads hoisted up front; every big reduction split across threads.
__global__ __launch_bounds__(512) void mlp_kernel(
    const float* __restrict__ W1, const float* __restrict__ b1,
    const float* __restrict__ W2, const float* __restrict__ b2,
    const float* __restrict__ W3, const float* __restrict__ b3,
    const float* __restrict__ W4, const float* __restrict__ b4,
    const float* __restrict__ W5, const float* __restrict__ b5,
    const float* __restrict__ W6, const float* __restrict__ b6,
    float* __restrict__ P)
{
    __shared__ float h1[16], h2[64], h3[256], h4[64], h5[16], z6[4];
    __shared__ float part[512];
    const int t = threadIdx.x;
    const float pos = (float)(blockIdx.x + 1);

    // ---- hoisted loads (addresses depend only on t; all in-bounds) ----
    float w1r = W1[t & 15];
    float b1r = b1[t & 15];

    const int o2 = t & 63;
    float4 w2r[4];
    {
        const float4* v = (const float4*)(W2 + o2 * 16);
        #pragma unroll
        for (int k = 0; k < 4; ++k) w2r[k] = v[k];
    }
    float b2r = b2[o2];

    const int o3 = t & 255, q3 = t >> 8;          // q3 in {0,1}, half-row each
    float4 w3r[8];
    {
        const float4* v = (const float4*)(W3 + o3 * 64 + q3 * 32);
        #pragma unroll
        for (int k = 0; k < 8; ++k) w3r[k] = v[k];
    }
    float b3r = b3[o3];

    const int o4 = t & 63, q4 = t >> 6;           // q4 in 0..7, eighth-row each
    float4 w4r[8];
    {
        const float4* v = (const float4*)(W4 + o4 * 256 + q4 * 32);
        #pragma unroll
        for (int k = 0; k < 8; ++k) w4r[k] = v[k];
    }
    float b4r = b4[o4];

    const int o5 = t & 15, q5 = (t >> 4) & 15;    // 16 partials per output
    float4 w5r = *(const float4*)(W5 + o5 * 64 + q5 * 4);
    float b5r = b5[o5];

    const int o6 = t & 3;
    float4 w6r[4];
    {
        const float4* v = (const float4*)(W6 + o6 * 16);
        #pragma unroll
        for (int k = 0; k < 4; ++k) w6r[k] = v[k];
    }
    float b6r = b6[o6];

    // ---- L1: (1 -> 16) sigmoid ----
    if (t < 16) h1[t] = sigm(fmaf(w1r, pos, b1r));
    __syncthreads();

    // ---- L2: (16 -> 64) sigmoid ----
    if (t < 64) {
        const float4* h = (const float4*)h1;
        float a = b2r + ((dot4(w2r[0], h[0]) + dot4(w2r[1], h[1])) +
                         (dot4(w2r[2], h[2]) + dot4(w2r[3], h[3])));
        h2[t] = sigm(a);
    }
    __syncthreads();

    // ---- L3: (64 -> 256) relu, 2 partials per output ----
    {
        const float4* h = (const float4*)(h2 + q3 * 32);
        float a0 = 0.f, a1 = 0.f, a2 = 0.f, a3 = 0.f;
        a0 = dot4(w3r[0], h[0]); a1 = dot4(w3r[1], h[1]);
        a2 = dot4(w3r[2], h[2]); a3 = dot4(w3r[3], h[3]);
        a0 += dot4(w3r[4], h[4]); a1 += dot4(w3r[5], h[5]);
        a2 += dot4(w3r[6], h[6]); a3 += dot4(w3r[7], h[7]);
        part[t] = (a0 + a1) + (a2 + a3);
    }
    __syncthreads();
    if (t < 256) h3[t] = fmaxf(b3r + part[t] + part[t + 256], 0.f);
    __syncthreads();

    // ---- L4: (256 -> 64) relu, 8 partials per output ----
    {
        const float4* h = (const float4*)(h3 + q4 * 32);
        float a0 = 0.f, a1 = 0.f, a2 = 0.f, a3 = 0.f;
        a0 = dot4(w4r[0], h[0]); a1 = dot4(w4r[1], h[1]);
        a2 = dot4(w4r[2], h[2]); a3 = dot4(w4r[3], h[3]);
        a0 += dot4(w4r[4], h[4]); a1 += dot4(w4r[5], h[5]);
        a2 += dot4(w4r[6], h[6]); a3 += dot4(w4r[7], h[7]);
        part[t] = (a0 + a1) + (a2 + a3);
    }
    __syncthreads();
    if (t < 64) {
        float s = ((part[t] + part[t + 64]) + (part[t + 128] + part[t + 192])) +
                  ((part[t + 256] + part[t + 320]) + (part[t + 384] + part[t + 448]));
        h4[t] = fmaxf(b4r + s, 0.f);
    }
    __syncthreads();

    // ---- L5: (64 -> 16) relu, 16 partials per output ----
    if (t < 256) part[t] = dot4(w5r, *(const float4*)(h4 + q5 * 4));
    __syncthreads();
    if (t < 16) {
        float s = 0.f;
        #pragma unroll
        for (int q = 0; q < 16; ++q) s += part[t + 16 * q];
        h5[t] = fmaxf(b5r + s, 0.f);
    }
    __syncthreads();

    // ---- L6: (16 -> 4) ----
    if (t < 4) {
        const float4* h = (const float4*)h5;
        z6[t] = b6r + ((dot4(w6r[0], h[0]) + dot4(w6r[1], h[1])) +
                       (dot4(w6r[2], h[2]) + dot4(w6r[3], h[3])));
    }
    __syncthreads();

    // ---- cumsum over dims, write P row ----
    if (t < 4) {
        float c = 0.f;
        #pragma unroll
        for (int j = 0; j <= 3; ++j) {
            float v = z6[j];
            if (j <= t) c += v;
        }
        P[blockIdx.x * NDIMS + t] = c;
    }
}

// ---------------- Kernel B: spline evaluation, power-basis coefficient table ----------------
// Row i (RSTRIDE floats): [Ac(4) Bc(4) Cc(4) GB(4) GC(4) pad(8)]
//   fc(d) = Ac + Bc*d + Cc*d^2          (curr Bezier in power basis)
//   fp(d) - fc(d) = d*(GB + GC*d)       (fp(0)==fc(0)==p0 by construction)
//   r = fc + wc*d*(GB + GC*d),  wc = cos^2(pi d) = 0.5 + 0.5*cos(2 pi d)
__global__ __launch_bounds__(256) void spline_kernel(
    const float* __restrict__ x, const float* __restrict__ P,
    float4* __restrict__ out4, int n)
{
    __shared__ float Praw[NPTS * NDIMS];
    __shared__ float s[NITER * RSTRIDE];
    const int t = threadIdx.x;

    if (t < NPTS * NDIMS) Praw[t] = P[t];
    __syncthreads();

    if (t < NDIMS) {
        const int j = t;
        float P0 = Praw[0 * NDIMS + j];
        float P1 = Praw[1 * NDIMS + j];
        float P2 = Praw[2 * NDIMS + j];
        #pragma unroll
        for (int i = 0; i < NITER; ++i) {
            float Pn = Praw[(3 + i) * NDIMS + j];
            // reference recurrence (bit-identical)
            float p0 = (P0 + P2) * 0.25f + P1 * 0.5f;
            float p2 = Pn;
            float p1 = 2.0f * (P2 - (p0 + p2) * 0.25f);
            // prev Bezier (P0,P1,P2) at dp=d+0.5, in powers of d:
            //   fp = p0 + (P2-P0)*d + (P0-2P1+P2)*d^2     (fp(0) = Bernstein(0.5) = p0)
            float Bp = P2 - P0;
            float Cp = (P0 + P2) - 2.0f * P1;
            // curr Bezier (p0,p1,p2) at d, in powers of d:
            float Bc = 2.0f * (p1 - p0);
            float Cc = (p0 + p2) - 2.0f * p1;
            float* row = s + i * RSTRIDE;
            row[0 * 4 + j] = p0;
            row[1 * 4 + j] = Bc;
            row[2 * 4 + j] = Cc;
            row[3 * 4 + j] = Bp - Bc;
            row[4 * 4 + j] = Cp - Cc;
            P0 = p0; P1 = p1; P2 = p2;
        }
    }
    __syncthreads();

    const int gstride = NBLK * CHUNK;
    for (int base = blockIdx.x * CHUNK; base < n; base += gstride) {
        #pragma unroll
        for (int k = 0; k < 4; ++k) {
            const int i = base + k * 256 + t;
            if (i < n) {
                float u  = x[i] * 15.0f;
                float fi = floorf(u);
                fi = fminf(fmaxf(fi, 0.0f), 14.0f);  // last matching choice == floor bucket
                float d  = (u - fi) * 0.5f;          // in [0, 0.5)

                const float* row = s + (int)fi * RSTRIDE;
                float4 Ac = *(const float4*)(row + 0);
                float4 Bc = *(const float4*)(row + 4);
                float4 Cc = *(const float4*)(row + 8);
                float4 GB = *(const float4*)(row + 12);
                float4 GC = *(const float4*)(row + 16);

                float wc  = fmaf(0.5f, cospif(2.0f * d), 0.5f);
                float wcd = wc * d;

                float4 r;
                r.x = fmaf(wcd, fmaf(d, GC.x, GB.x), fmaf(d, fmaf(d, Cc.x, Bc.x), Ac.x));
                r.y = fmaf(wcd, fmaf(d, GC.y, GB.y), fmaf(d, fmaf(d, Cc.y, Bc.y), Ac.y));
                r.z = fmaf(wcd, fmaf(d, GC.z, GB.z), fmaf(d, fmaf(d, Cc.z, Bc.z), Ac.z));
                r.w = fmaf(wcd, fmaf(d, GC.w, GB.w), fmaf(d, fmaf(d, Cc.w, Bc.w), Ac.w));

                out4[i] = r;
            }
        }
    }
}

// ---------------- launch ----------------
extern "C" void kernel_launch(void* const* d_in, const int* in_sizes, int n_in,
                              void* d_out, int out_size, void* d_ws, size_t ws_size,
                              hipStream_t stream)
{
    const float* x  = (const float*)d_in[0];
    const float* W1 = (const float*)d_in[1];  const float* b1 = (const float*)d_in[2];
    const float* W2 = (const float*)d_in[3];  const float* b2 = (const float*)d_in[4];
    const float* W3 = (const float*)d_in[5];  const float* b3 = (const float*)d_in[6];
    const float* W4 = (const float*)d_in[7];  const float* b4 = (const float*)d_in[8];
    const float* W5 = (const float*)d_in[9];  const float* b5 = (const float*)d_in[10];
    const float* W6 = (const float*)d_in[11]; const float* b6 = (const float*)d_in[12];

    float* P = (float*)d_ws;   // 72 floats
    const int n = in_sizes[0];

    mlp_kernel<<<NPTS, 512, 0, stream>>>(W1, b1, W2, b2, W3, b3, W4, b4, W5, b5, W6, b6, P);

    const int blocks = min(NBLK, (n + CHUNK - 1) / CHUNK);
    spline_kernel<<<blocks, 256, 0, stream>>>(x, P, (float4*)d_out, n);
}